// Round 1
// baseline (472.718 us; speedup 1.0000x reference)
//
#include <hip/hip_runtime.h>
#include <cstdint>

// ---------------------------------------------------------------------------
// MLA prefill: B=2, S=2048, D=2048, H=16, NOPE=128, ROPE=64, VDIM=128,
// QKD=192, KV_RANK=512. Full (non-causal) attention. FP16 MFMA compute.
// ---------------------------------------------------------------------------

typedef _Float16 f16;
typedef _Float16 f16x8 __attribute__((ext_vector_type(8)));
typedef _Float16 f16x4 __attribute__((ext_vector_type(4)));
typedef float    f32x4 __attribute__((ext_vector_type(4)));

#define S_TOK 2048
#define TOK   4096            // B*S
#define SCALE 0.07216878364870322f   // 192^-0.5

// async global->LDS, 16B per lane; LDS base must be wave-uniform.
__device__ __forceinline__ void gl2lds16(const void* g, void* lds_wave_base) {
  __builtin_amdgcn_global_load_lds(
      (const __attribute__((address_space(1))) uint32_t*)(uintptr_t)g,
      (__attribute__((address_space(3))) uint32_t*)(uint32_t)(uintptr_t)lds_wave_base,
      16, 0, 0);
}

// ---------------------------------------------------------------------------
// converts
// ---------------------------------------------------------------------------
__global__ __launch_bounds__(256) void k_cvt(
    const float* __restrict__ x, const float* __restrict__ wq,
    const float* __restrict__ wkvb, const float* __restrict__ wo,
    f16* __restrict__ xb, f16* __restrict__ wqb,
    f16* __restrict__ wkvbb, f16* __restrict__ wob)
{
  size_t i = ((size_t)blockIdx.x * 256 + threadIdx.x) * 4;
  const float* src; f16* dst; size_t off;
  if (i < 8388608ull)            { src = x;    dst = xb;    off = i; }
  else if (i < 14680064ull)      { src = wq;   dst = wqb;   off = i - 8388608ull; }
  else if (i < 16777216ull)      { src = wkvb; dst = wkvbb; off = i - 14680064ull; }
  else                           { src = wo;   dst = wob;   off = i - 16777216ull; }
  float4 v = *(const float4*)(src + off);
  f16x4 h; h[0]=(f16)v.x; h[1]=(f16)v.y; h[2]=(f16)v.z; h[3]=(f16)v.w;
  *(f16x4*)(dst + off) = h;
}

// wkv_a (576x2048) -> f16 padded to 640 rows (zeros)
__global__ __launch_bounds__(256) void k_cvt_pad(const float* __restrict__ w,
                                                 f16* __restrict__ out)
{
  int i = (blockIdx.x * 256 + threadIdx.x) * 4;   // < 640*2048
  int r = i >> 11;
  f16x4 h;
  if (r < 576) {
    float4 v = *(const float4*)(w + i);
    h[0]=(f16)v.x; h[1]=(f16)v.y; h[2]=(f16)v.z; h[3]=(f16)v.w;
  } else { h[0]=h[1]=h[2]=h[3]=(f16)0.f; }
  *(f16x4*)(out + i) = h;
}

// ---------------------------------------------------------------------------
// NT GEMM core: C[128 x 128] = A[128 x K] * B[128 x K]^T   (f16 in, 16x16x32)
// 256 threads = 4 waves in 2x2; each wave 64x64 (4x4 MFMA tiles).
// LDS tiles 128x64 f16, XOR-swizzled in 16B chunks: slot(r,sc)=global(r,sc^(r&7))
// ---------------------------------------------------------------------------
template<bool OUT_F16>
__device__ __forceinline__ void gemm_core(const f16* __restrict__ Ablk,
                                          const f16* __restrict__ Bblk,
                                          char* __restrict__ Cblk,
                                          int K, int ldc)
{
  __shared__ __align__(16) f16 As[128 * 64];
  __shared__ __align__(16) f16 Bs[128 * 64];

  const int tid  = threadIdx.x;
  const int lane = tid & 63;
  const int wv   = tid >> 6;
  const int wm = (wv >> 1) * 64, wn = (wv & 1) * 64;
  const int lrow = lane & 15;     // m/n within 16-tile (A/B operand row)
  const int lk   = lane >> 4;     // k-group 0..3

  f32x4 acc[4][4];
#pragma unroll
  for (int i = 0; i < 4; ++i)
#pragma unroll
    for (int j = 0; j < 4; ++j) acc[i][j] = f32x4{0.f, 0.f, 0.f, 0.f};

  for (int k0 = 0; k0 < K; k0 += 64) {
    __syncthreads();
#pragma unroll
    for (int it = 0; it < 4; ++it) {
      int s  = it * 256 + tid;            // chunk 0..1023 (16B chunks)
      int r  = s >> 3, sc = s & 7;
      int gc = sc ^ (r & 7);
      f16* lbase = (f16*)As + (size_t)(it * 256 + wv * 64) * 8;
      gl2lds16(Ablk + (size_t)r * K + k0 + gc * 8, lbase);
      f16* lbase2 = (f16*)Bs + (size_t)(it * 256 + wv * 64) * 8;
      gl2lds16(Bblk + (size_t)r * K + k0 + gc * 8, lbase2);
    }
    __syncthreads();

#pragma unroll
    for (int ks = 0; ks < 2; ++ks) {
      f16x8 af[4], bf[4];
#pragma unroll
      for (int i = 0; i < 4; ++i) {
        int ra = wm + i * 16 + lrow;
        int ca = (ks * 4 + lk) ^ (ra & 7);
        af[i] = *(const f16x8*)(As + ra * 64 + ca * 8);
        int rb = wn + i * 16 + lrow;
        int cb = (ks * 4 + lk) ^ (rb & 7);
        bf[i] = *(const f16x8*)(Bs + rb * 64 + cb * 8);
      }
#pragma unroll
      for (int i = 0; i < 4; ++i)
#pragma unroll
        for (int j = 0; j < 4; ++j)
          acc[i][j] = __builtin_amdgcn_mfma_f32_16x16x32_f16(af[i], bf[j], acc[i][j], 0, 0, 0);
    }
  }

  // C/D layout: row=(lane>>4)*4+reg, col=lane&15
#pragma unroll
  for (int i = 0; i < 4; ++i)
#pragma unroll
    for (int rr = 0; rr < 4; ++rr) {
      int row = wm + i * 16 + lk * 4 + rr;
#pragma unroll
      for (int j = 0; j < 4; ++j) {
        int col = wn + j * 16 + lrow;
        if constexpr (OUT_F16)
          ((f16*)Cblk)[(size_t)row * ldc + col] = (f16)acc[i][j][rr];
        else
          ((float*)Cblk)[(size_t)row * ldc + col] = acc[i][j][rr];
      }
    }
}

template<bool OUT_F16>
__global__ __launch_bounds__(256, 3) void k_gemm_nt(
    const f16* __restrict__ A, const f16* __restrict__ Bw,
    void* __restrict__ C, int K, int ldc)
{
  int m0 = blockIdx.y * 128, n0 = blockIdx.x * 128;
  gemm_core<OUT_F16>(A + (size_t)m0 * K, Bw + (size_t)n0 * K,
                     (char*)C + ((size_t)m0 * ldc + n0) * (OUT_F16 ? 2 : 4),
                     K, ldc);
}

// fused Q-proj (N=3072) + KV-a proj (N=640 padded): 29 n-tiles
__global__ __launch_bounds__(256, 3) void k_gemm_qkva(
    const f16* __restrict__ xb, const f16* __restrict__ wqb,
    const f16* __restrict__ wkvab, f16* __restrict__ qraw, f16* __restrict__ kva)
{
  int nb = blockIdx.x, m0 = blockIdx.y * 128;
  const f16* Bblk; f16* Cb; int ldc;
  if (nb < 24) { Bblk = wqb + (size_t)nb * 128 * 2048;
                 Cb = qraw + (size_t)m0 * 3072 + nb * 128; ldc = 3072; }
  else         { int n0 = (nb - 24) * 128;
                 Bblk = wkvab + (size_t)n0 * 2048;
                 Cb = kva + (size_t)m0 * 640 + n0; ldc = 640; }
  gemm_core<true>(xb + (size_t)m0 * 2048, Bblk, (char*)Cb, 2048, ldc);
}

// ---------------------------------------------------------------------------
// RMSNorm over KV_RANK=512 (kva has 640 cols; cols 512..575 = k_pe)
// ---------------------------------------------------------------------------
__global__ __launch_bounds__(256) void k_rmsnorm(const f16* __restrict__ kva,
                                                 const float* __restrict__ w,
                                                 f16* __restrict__ kvn)
{
  int row = blockIdx.x;
  const f16* in = kva + (size_t)row * 640;
  int t = threadIdx.x;
  float v0 = (float)in[t], v1 = (float)in[t + 256];
  float ss = v0 * v0 + v1 * v1;
#pragma unroll
  for (int m = 1; m < 64; m <<= 1) ss += __shfl_xor(ss, m);
  __shared__ float red[4];
  if ((t & 63) == 0) red[t >> 6] = ss;
  __syncthreads();
  float tot = red[0] + red[1] + red[2] + red[3];
  float sc = rsqrtf(tot * (1.0f / 512.0f) + 1e-6f);
  kvn[(size_t)row * 512 + t]       = (f16)(v0 * sc * w[t]);
  kvn[(size_t)row * 512 + t + 256] = (f16)(v1 * sc * w[t + 256]);
}

// ---------------------------------------------------------------------------
// pack Q: qraw (tok,3072) -> qf (b,h,s,192) with RoPE on dims 128..191
// ---------------------------------------------------------------------------
__global__ __launch_bounds__(256) void k_pack_q(const f16* __restrict__ qraw,
                                                const float* __restrict__ cosb,
                                                const float* __restrict__ sinb,
                                                f16* __restrict__ qf)
{
  int row = blockIdx.x;              // token
  int b = row >> 11, s = row & 2047;
  const f16* qr = qraw + (size_t)row * 3072;
#pragma unroll
  for (int it = 0; it < 12; ++it) {
    int idx = it * 256 + threadIdx.x;     // 0..3071
    int h = idx / 192, d = idx - h * 192;
    float val;
    if (d < 128) val = (float)qr[idx];
    else {
      int j = d - 128;
      float xv = (float)qr[idx];
      float part = (j < 32) ? -(float)qr[idx + 32] : (float)qr[idx - 32];
      val = xv * cosb[s * 64 + j] + part * sinb[s * 64 + j];
    }
    qf[((size_t)(b * 16 + h) * 2048 + s) * 192 + d] = (f16)val;
  }
}

// pack K: kvproj nope + broadcast roped k_pe -> kf (b,h,s,192)
__global__ __launch_bounds__(256) void k_pack_k(const f16* __restrict__ kvproj,
                                                const f16* __restrict__ kva,
                                                const float* __restrict__ cosb,
                                                const float* __restrict__ sinb,
                                                f16* __restrict__ kf)
{
  int row = blockIdx.x;
  int b = row >> 11, s = row & 2047;
  const f16* kp = kvproj + (size_t)row * 4096;
  const f16* pe = kva + (size_t)row * 640 + 512;
#pragma unroll
  for (int it = 0; it < 12; ++it) {
    int idx = it * 256 + threadIdx.x;
    int h = idx / 192, d = idx - h * 192;
    float val;
    if (d < 128) val = (float)kp[h * 256 + d];
    else {
      int j = d - 128;
      float xv = (float)pe[j];
      float part = (j < 32) ? -(float)pe[j + 32] : (float)pe[j - 32];
      val = xv * cosb[s * 64 + j] + part * sinb[s * 64 + j];
    }
    kf[((size_t)(b * 16 + h) * 2048 + s) * 192 + d] = (f16)val;
  }
}

// pack V transposed: kvproj v-part -> vf (b,h, 128 vdim, 2048 s)
__global__ __launch_bounds__(256) void k_pack_v(const f16* __restrict__ kvproj,
                                                f16* __restrict__ vf)
{
  int st = blockIdx.x, h = blockIdx.y, b = blockIdx.z;
  int s0 = st * 64;
  __shared__ f16 tbuf[64 * 130];
  const f16* src = kvproj + ((size_t)(b * 2048 + s0)) * 4096 + h * 256 + 128;
#pragma unroll
  for (int it = 0; it < 32; ++it) {
    int idx = it * 256 + threadIdx.x;   // 64 x 128
    int sr = idx >> 7, jc = idx & 127;
    tbuf[sr * 130 + jc] = src[(size_t)sr * 4096 + jc];
  }
  __syncthreads();
  f16* dst = vf + ((size_t)(b * 16 + h) * 128) * 2048 + s0;
#pragma unroll
  for (int it = 0; it < 32; ++it) {
    int idx = it * 256 + threadIdx.x;   // 128 x 64
    int jr = idx >> 6, scc = idx & 63;
    dst[(size_t)jr * 2048 + scc] = tbuf[scc * 130 + jr];
  }
}

// ---------------------------------------------------------------------------
// flash attention: per block (q-tile 64, h, b); waves own 16 q-rows each.
// K tiles 64x192, V^T tiles 128x64 staged via global_load_lds (swizzled).
// ---------------------------------------------------------------------------
__global__ __launch_bounds__(256, 2) void k_attn(const f16* __restrict__ qf,
                                                 const f16* __restrict__ kf,
                                                 const f16* __restrict__ vf,
                                                 f16* __restrict__ aout)
{
  int qt = blockIdx.x, h = blockIdx.y, b = blockIdx.z;
  int bh = b * 16 + h;
  int q0 = qt * 64;
  int tid = threadIdx.x, lane = tid & 63, wv = tid >> 6;
  int lrow = lane & 15, lk = lane >> 4;

  __shared__ __align__(16) f16 Ks[64 * 192];
  __shared__ __align__(16) f16 Vs[128 * 64];
  __shared__ __align__(16) f16 Ps[4][16 * 72];   // per-wave P strip, padded

  // preload Q A-frags: rows q0+wv*16+lrow, 6 ksteps of 32
  const f16* qbase = qf + ((size_t)bh * 2048 + q0 + wv * 16 + lrow) * 192 + lk * 8;
  f16x8 qfr[6];
#pragma unroll
  for (int ks = 0; ks < 6; ++ks) qfr[ks] = *(const f16x8*)(qbase + ks * 32);

  f32x4 oacc[8];
#pragma unroll
  for (int i = 0; i < 8; ++i) oacc[i] = f32x4{0.f, 0.f, 0.f, 0.f};
  float m_st[4] = {-1e30f, -1e30f, -1e30f, -1e30f};
  float l_st[4] = {0.f, 0.f, 0.f, 0.f};

  const f16* kbase = kf + (size_t)bh * 2048 * 192;
  const f16* vbase = vf + (size_t)bh * 128 * 2048;

  for (int t0 = 0; t0 < 2048; t0 += 64) {
    __syncthreads();
    // stage K tile: 64 rows x 24 chunks = 1536 chunks
#pragma unroll
    for (int it = 0; it < 6; ++it) {
      unsigned s = it * 256 + tid;
      unsigned r = s / 24u, c24 = s - r * 24u;
      unsigned gc = c24 ^ (r & 7u);
      f16* lbase = (f16*)Ks + (size_t)(it * 256 + wv * 64) * 8;
      gl2lds16(kbase + (size_t)(t0 + r) * 192 + gc * 8, lbase);
    }
    // stage V^T tile: 128 rows x 8 chunks = 1024 chunks
#pragma unroll
    for (int it = 0; it < 4; ++it) {
      int s = it * 256 + tid;
      int r = s >> 3, scv = s & 7;
      int gc = scv ^ (r & 7);
      f16* lbase = (f16*)Vs + (size_t)(it * 256 + wv * 64) * 8;
      gl2lds16(vbase + (size_t)r * 2048 + t0 + gc * 8, lbase);
    }
    __syncthreads();

    // S = Q K^T : wave's 16 rows x 64 keys
    f32x4 sacc[4];
#pragma unroll
    for (int nt = 0; nt < 4; ++nt) {
      f32x4 a = f32x4{0.f, 0.f, 0.f, 0.f};
#pragma unroll
      for (int ks = 0; ks < 6; ++ks) {
        int rb = nt * 16 + lrow;
        int cc = (ks * 4 + lk) ^ (rb & 7);
        f16x8 bfr = *(const f16x8*)(Ks + rb * 192 + cc * 8);
        a = __builtin_amdgcn_mfma_f32_16x16x32_f16(qfr[ks], bfr, a, 0, 0, 0);
      }
      sacc[nt] = a;
    }

    // online softmax per row (row = lk*4+r, cols across 16 lanes x 4 tiles)
    float alpha[4];
#pragma unroll
    for (int r = 0; r < 4; ++r) {
      float z0 = sacc[0][r] * SCALE, z1 = sacc[1][r] * SCALE;
      float z2 = sacc[2][r] * SCALE, z3 = sacc[3][r] * SCALE;
      float mx = fmaxf(fmaxf(z0, z1), fmaxf(z2, z3));
#pragma unroll
      for (int msk = 1; msk < 16; msk <<= 1) mx = fmaxf(mx, __shfl_xor(mx, msk));
      float mnew = fmaxf(m_st[r], mx);
      float al = __expf(m_st[r] - mnew);
      float p0 = __expf(z0 - mnew), p1 = __expf(z1 - mnew);
      float p2 = __expf(z2 - mnew), p3 = __expf(z3 - mnew);
      float ls = p0 + p1 + p2 + p3;
#pragma unroll
      for (int msk = 1; msk < 16; msk <<= 1) ls += __shfl_xor(ls, msk);
      l_st[r] = l_st[r] * al + ls;
      m_st[r] = mnew;
      alpha[r] = al;
      int prow = (lk * 4 + r) * 72;
      Ps[wv][prow + 0 * 16 + lrow] = (f16)p0;
      Ps[wv][prow + 1 * 16 + lrow] = (f16)p1;
      Ps[wv][prow + 2 * 16 + lrow] = (f16)p2;
      Ps[wv][prow + 3 * 16 + lrow] = (f16)p3;
    }
#pragma unroll
    for (int nv = 0; nv < 8; ++nv) {
      oacc[nv][0] *= alpha[0]; oacc[nv][1] *= alpha[1];
      oacc[nv][2] *= alpha[2]; oacc[nv][3] *= alpha[3];
    }
    __builtin_amdgcn_s_waitcnt(0xC07F);   // lgkmcnt(0): P writes visible to own wave

    // O += P V : P strip 16x64 (A-layout from LDS), V^T rows = vdim
#pragma unroll
    for (int ks2 = 0; ks2 < 2; ++ks2) {
      f16x8 pa = *(const f16x8*)(&Ps[wv][lrow * 72 + ks2 * 32 + lk * 8]);
#pragma unroll
      for (int nv = 0; nv < 8; ++nv) {
        int rv = nv * 16 + lrow;
        int cc = (ks2 * 4 + lk) ^ (rv & 7);
        f16x8 vb = *(const f16x8*)(Vs + rv * 64 + cc * 8);
        oacc[nv] = __builtin_amdgcn_mfma_f32_16x16x32_f16(pa, vb, oacc[nv], 0, 0, 0);
      }
    }
  }

  float rinv[4];
#pragma unroll
  for (int r = 0; r < 4; ++r) rinv[r] = 1.0f / l_st[r];
  f16* ob = aout + ((size_t)(b * 2048 + q0 + wv * 16 + lk * 4)) * 2048 + h * 128 + lrow;
#pragma unroll
  for (int nv = 0; nv < 8; ++nv)
#pragma unroll
    for (int rr = 0; rr < 4; ++rr)
      ob[(size_t)rr * 2048 + nv * 16] = (f16)(oacc[nv][rr] * rinv[rr]);
}

// ---------------------------------------------------------------------------
extern "C" void kernel_launch(void* const* d_in, const int* in_sizes, int n_in,
                              void* d_out, int out_size, void* d_ws, size_t ws_size,
                              hipStream_t stream)
{
  const float* x    = (const float*)d_in[0];
  const float* cosb = (const float*)d_in[1];
  const float* sinb = (const float*)d_in[2];
  const float* wq   = (const float*)d_in[3];
  const float* wkva = (const float*)d_in[4];
  const float* knw  = (const float*)d_in[5];
  const float* wkvb = (const float*)d_in[6];
  const float* wo   = (const float*)d_in[7];
  float* out = (float*)d_out;

  char* p = (char*)d_ws;
  auto take = [&](size_t bytes) { char* r = p; p += (bytes + 255) & ~(size_t)255; return r; };
  f16* xb     = (f16*)take(8388608ull * 2);    // x f16          (4096x2048)
  f16* wqb    = (f16*)take(6291456ull * 2);    // wq f16         (3072x2048)
  f16* wkvab  = (f16*)take(1310720ull * 2);    // wkv_a padded   (640x2048)
  f16* wkvbb  = (f16*)take(2097152ull * 2);    // wkv_b f16      (4096x512)
  f16* wob    = (f16*)take(4194304ull * 2);    // wo f16         (2048x2048)
  f16* qraw   = (f16*)take(12582912ull * 2);   // q proj         (4096x3072)
  f16* kva    = (f16*)take(2621440ull * 2);    // kv_a out       (4096x640)
  f16* kvn    = (f16*)take(2097152ull * 2);    // rmsnormed kv   (4096x512)
  f16* kvproj = (f16*)take(16777216ull * 2);   // kv_b out       (4096x4096)
  f16* qf     = (f16*)take(12582912ull * 2);   // (b,h,s,192)
  f16* kf     = (f16*)take(12582912ull * 2);   // (b,h,s,192)
  f16* vf     = (f16*)take(8388608ull * 2);    // (b,h,128,s)  V^T
  f16* aout   = (f16*)take(8388608ull * 2);    // attn out (tok, 2048)

  k_cvt<<<20480, 256, 0, stream>>>(x, wq, wkvb, wo, xb, wqb, wkvbb, wob);
  k_cvt_pad<<<1280, 256, 0, stream>>>(wkva, wkvab);
  k_gemm_qkva<<<dim3(29, 32), 256, 0, stream>>>(xb, wqb, wkvab, qraw, kva);
  k_rmsnorm<<<4096, 256, 0, stream>>>(kva, knw, kvn);
  k_gemm_nt<true><<<dim3(32, 32), 256, 0, stream>>>(kvn, wkvbb, kvproj, 512, 4096);
  k_pack_q<<<4096, 256, 0, stream>>>(qraw, cosb, sinb, qf);
  k_pack_k<<<4096, 256, 0, stream>>>(kvproj, kva, cosb, sinb, kf);
  k_pack_v<<<dim3(32, 16, 2), 256, 0, stream>>>(kvproj, vf);
  k_attn<<<dim3(32, 16, 2), 256, 0, stream>>>(qf, kf, vf, aout);
  k_gemm_nt<false><<<dim3(16, 32), 256, 0, stream>>>(aout, wob, out, 2048, 2048);
}

// Round 4
// 443.907 us; speedup vs baseline: 1.0649x; 1.0649x over previous
//
#include <hip/hip_runtime.h>
#include <cstdint>

// ---------------------------------------------------------------------------
// MLA prefill: B=2, S=2048, D=2048, H=16, NOPE=128, ROPE=64, VDIM=128,
// QKD=192, KV_RANK=512. Full (non-causal) attention. FP16 MFMA compute.
// R4 = R3 + vf workspace size fix (was 4M elems, needs 8M; tail aliased aout
//      -> b=1 V clobbered by b=0 attention outputs -> 2.3e-2 error).
// ---------------------------------------------------------------------------

typedef _Float16 f16;
typedef _Float16 f16x8 __attribute__((ext_vector_type(8)));
typedef _Float16 f16x4 __attribute__((ext_vector_type(4)));
typedef float    f32x4 __attribute__((ext_vector_type(4)));

#define SCALE 0.07216878364870322f   // 192^-0.5

__device__ __forceinline__ void gl2lds16(const void* g, void* lds_wave_base) {
  __builtin_amdgcn_global_load_lds(
      (const __attribute__((address_space(1))) uint32_t*)(uintptr_t)g,
      (__attribute__((address_space(3))) uint32_t*)(uint32_t)(uintptr_t)lds_wave_base,
      16, 0, 0);
}

// ---------------------------------------------------------------------------
// converts
// ---------------------------------------------------------------------------
__global__ __launch_bounds__(256) void k_cvt(
    const float* __restrict__ x, const float* __restrict__ wq,
    const float* __restrict__ wkvb, const float* __restrict__ wo,
    f16* __restrict__ xb, f16* __restrict__ wqb,
    f16* __restrict__ wkvbb, f16* __restrict__ wob)
{
  size_t i = ((size_t)blockIdx.x * 256 + threadIdx.x) * 4;
  const float* src; f16* dst; size_t off;
  if (i < 8388608ull)            { src = x;    dst = xb;    off = i; }
  else if (i < 14680064ull)      { src = wq;   dst = wqb;   off = i - 8388608ull; }
  else if (i < 16777216ull)      { src = wkvb; dst = wkvbb; off = i - 14680064ull; }
  else                           { src = wo;   dst = wob;   off = i - 16777216ull; }
  float4 v = *(const float4*)(src + off);
  f16x4 h; h[0]=(f16)v.x; h[1]=(f16)v.y; h[2]=(f16)v.z; h[3]=(f16)v.w;
  *(f16x4*)(dst + off) = h;
}

// wkv_a (576x2048) -> f16 padded to 640 rows (zeros)
__global__ __launch_bounds__(256) void k_cvt_pad(const float* __restrict__ w,
                                                 f16* __restrict__ out)
{
  int i = (blockIdx.x * 256 + threadIdx.x) * 4;
  int r = i >> 11;
  f16x4 h;
  if (r < 576) {
    float4 v = *(const float4*)(w + i);
    h[0]=(f16)v.x; h[1]=(f16)v.y; h[2]=(f16)v.z; h[3]=(f16)v.w;
  } else { h[0]=h[1]=h[2]=h[3]=(f16)0.f; }
  *(f16x4*)(out + i) = h;
}

// ---------------------------------------------------------------------------
// NT GEMM core: C[128x128] = A[128xK] * B[128xK]^T, custom epilogue functor.
// 4 waves 2x2; wave 64x64 via 4x4 MFMA 16x16x32. XOR-swizzled LDS tiles.
// ---------------------------------------------------------------------------
template<class Epi>
__device__ __forceinline__ void gemm_core(const f16* __restrict__ Ablk,
                                          const f16* __restrict__ Bblk,
                                          int K, Epi epi)
{
  __shared__ __align__(16) f16 As[128 * 64];
  __shared__ __align__(16) f16 Bs[128 * 64];

  const int tid  = threadIdx.x;
  const int lane = tid & 63;
  const int wv   = tid >> 6;
  const int wm = (wv >> 1) * 64, wn = (wv & 1) * 64;
  const int lrow = lane & 15;
  const int lk   = lane >> 4;

  f32x4 acc[4][4];
#pragma unroll
  for (int i = 0; i < 4; ++i)
#pragma unroll
    for (int j = 0; j < 4; ++j) acc[i][j] = f32x4{0.f, 0.f, 0.f, 0.f};

  for (int k0 = 0; k0 < K; k0 += 64) {
    __syncthreads();
#pragma unroll
    for (int it = 0; it < 4; ++it) {
      int s  = it * 256 + tid;
      int r  = s >> 3, sc = s & 7;
      int gc = sc ^ (r & 7);
      gl2lds16(Ablk + (size_t)r * K + k0 + gc * 8, (f16*)As + (size_t)(it * 256 + wv * 64) * 8);
      gl2lds16(Bblk + (size_t)r * K + k0 + gc * 8, (f16*)Bs + (size_t)(it * 256 + wv * 64) * 8);
    }
    __syncthreads();

#pragma unroll
    for (int ks = 0; ks < 2; ++ks) {
      f16x8 af[4], bf[4];
#pragma unroll
      for (int i = 0; i < 4; ++i) {
        int ra = wm + i * 16 + lrow;
        int ca = (ks * 4 + lk) ^ (ra & 7);
        af[i] = *(const f16x8*)(As + ra * 64 + ca * 8);
        int rb = wn + i * 16 + lrow;
        int cb = (ks * 4 + lk) ^ (rb & 7);
        bf[i] = *(const f16x8*)(Bs + rb * 64 + cb * 8);
      }
#pragma unroll
      for (int i = 0; i < 4; ++i)
#pragma unroll
        for (int j = 0; j < 4; ++j)
          acc[i][j] = __builtin_amdgcn_mfma_f32_16x16x32_f16(af[i], bf[j], acc[i][j], 0, 0, 0);
    }
  }
  epi(acc, wm, wn, lk, lrow);
}

// fused Q-proj (N=3072) + KV-a proj (N=640 padded)
__global__ __launch_bounds__(256, 3) void k_gemm_qkva(
    const f16* __restrict__ xb, const f16* __restrict__ wqb,
    const f16* __restrict__ wkvab, f16* __restrict__ qraw, f16* __restrict__ kva)
{
  int nb = blockIdx.x, m0 = blockIdx.y * 128;
  const f16* Bblk; f16* Cb; int ldc;
  if (nb < 24) { Bblk = wqb + (size_t)nb * 128 * 2048;
                 Cb = qraw + (size_t)m0 * 3072 + nb * 128; ldc = 3072; }
  else         { int n0 = (nb - 24) * 128;
                 Bblk = wkvab + (size_t)n0 * 2048;
                 Cb = kva + (size_t)m0 * 640 + n0; ldc = 640; }
  gemm_core(xb + (size_t)m0 * 2048, Bblk, 2048,
    [&](f32x4 (&acc)[4][4], int wm, int wn, int lk, int lrow) {
#pragma unroll
      for (int i = 0; i < 4; ++i)
#pragma unroll
        for (int rr = 0; rr < 4; ++rr) {
          int row = wm + i * 16 + lk * 4 + rr;
#pragma unroll
          for (int j = 0; j < 4; ++j)
            Cb[(size_t)row * ldc + wn + j * 16 + lrow] = (f16)acc[i][j][rr];
        }
    });
}

// kv_b proj: even n-tiles -> knope (tok,2048); odd n-tiles -> vf transposed (b,h,128,2048)
__global__ __launch_bounds__(256, 3) void k_gemm_kvb(
    const f16* __restrict__ kvn, const f16* __restrict__ wkvbb,
    f16* __restrict__ knope, f16* __restrict__ vf)
{
  int nb = blockIdx.x, m0 = blockIdx.y * 128;
  int hh = nb >> 1;
  bool isv = nb & 1;
  gemm_core(kvn + (size_t)m0 * 512, wkvbb + (size_t)nb * 128 * 512, 512,
    [&](f32x4 (&acc)[4][4], int wm, int wn, int lk, int lrow) {
      if (isv) {
#pragma unroll
        for (int i = 0; i < 4; ++i)
#pragma unroll
          for (int j = 0; j < 4; ++j) {
            int vd = wn + j * 16 + lrow;
            int trow = m0 + wm + i * 16 + lk * 4;
            int bb = trow >> 11, ss = trow & 2047;
            f16x4 pk;
#pragma unroll
            for (int rr = 0; rr < 4; ++rr) pk[rr] = (f16)acc[i][j][rr];
            *(f16x4*)(vf + ((size_t)(bb * 16 + hh) * 128 + vd) * 2048 + ss) = pk;
          }
      } else {
#pragma unroll
        for (int i = 0; i < 4; ++i)
#pragma unroll
          for (int rr = 0; rr < 4; ++rr) {
            int trow = m0 + wm + i * 16 + lk * 4 + rr;
#pragma unroll
            for (int j = 0; j < 4; ++j)
              knope[(size_t)trow * 2048 + hh * 128 + wn + j * 16 + lrow] = (f16)acc[i][j][rr];
          }
      }
    });
}

// O-proj, fp32 out
__global__ __launch_bounds__(256, 3) void k_gemm_out(
    const f16* __restrict__ aout, const f16* __restrict__ wob, float* __restrict__ out)
{
  int n0 = blockIdx.x * 128, m0 = blockIdx.y * 128;
  gemm_core(aout + (size_t)m0 * 2048, wob + (size_t)n0 * 2048, 2048,
    [&](f32x4 (&acc)[4][4], int wm, int wn, int lk, int lrow) {
#pragma unroll
      for (int i = 0; i < 4; ++i)
#pragma unroll
        for (int rr = 0; rr < 4; ++rr) {
          int row = m0 + wm + i * 16 + lk * 4 + rr;
#pragma unroll
          for (int j = 0; j < 4; ++j)
            out[(size_t)row * 2048 + n0 + wn + j * 16 + lrow] = acc[i][j][rr];
        }
    });
}

// ---------------------------------------------------------------------------
// RMSNorm over KV_RANK=512 + RoPE on the 64 k_pe dims -> kper
// ---------------------------------------------------------------------------
__global__ __launch_bounds__(256) void k_rmsnorm_rope(
    const f16* __restrict__ kva, const float* __restrict__ w,
    const float* __restrict__ cosb, const float* __restrict__ sinb,
    f16* __restrict__ kvn, f16* __restrict__ kper)
{
  int row = blockIdx.x;
  int s = row & 2047;
  const f16* in = kva + (size_t)row * 640;
  int t = threadIdx.x;
  float v0 = (float)in[t], v1 = (float)in[t + 256];
  float ss = v0 * v0 + v1 * v1;
#pragma unroll
  for (int m = 1; m < 64; m <<= 1) ss += __shfl_xor(ss, m);
  __shared__ float red[4];
  if ((t & 63) == 0) red[t >> 6] = ss;
  __syncthreads();
  float tot = red[0] + red[1] + red[2] + red[3];
  float sc = rsqrtf(tot * (1.0f / 512.0f) + 1e-6f);
  kvn[(size_t)row * 512 + t]       = (f16)(v0 * sc * w[t]);
  kvn[(size_t)row * 512 + t + 256] = (f16)(v1 * sc * w[t + 256]);
  if (t < 32) {
    float a = (float)in[512 + t], bq = (float)in[512 + t + 32];
    float c0 = cosb[s * 64 + t], s0 = sinb[s * 64 + t];
    float c1 = cosb[s * 64 + t + 32], s1 = sinb[s * 64 + t + 32];
    kper[(size_t)row * 64 + t]      = (f16)(a * c0 - bq * s0);
    kper[(size_t)row * 64 + t + 32] = (f16)(bq * c1 + a * s1);
  }
}

// RoPE on q_pe slices of qraw, in place. One thread per (token,h,pair j<32).
__global__ __launch_bounds__(256) void k_rope_q(
    f16* __restrict__ qraw, const float* __restrict__ cosb, const float* __restrict__ sinb)
{
  int idx = blockIdx.x * 256 + threadIdx.x;   // < 4096*16*32
  int j = idx & 31;
  int hh = (idx >> 5) & 15;
  int t = idx >> 9;
  int s = t & 2047;
  f16* base = qraw + (size_t)t * 3072 + hh * 192 + 128;
  float a = (float)base[j], bq = (float)base[j + 32];
  float c0 = cosb[s * 64 + j], s0 = sinb[s * 64 + j];
  float c1 = cosb[s * 64 + j + 32], s1 = sinb[s * 64 + j + 32];
  base[j]      = (f16)(a * c0 - bq * s0);
  base[j + 32] = (f16)(bq * c1 + a * s1);
}

// ---------------------------------------------------------------------------
// flash attention: block = (q-tile 128, h, b); 4 waves, wave owns 32 q-rows.
// K staged from knope+kper (two-source swizzled tile), V^T from vf.
// ---------------------------------------------------------------------------
__global__ __launch_bounds__(256, 2) void k_attn(
    const f16* __restrict__ qraw, const f16* __restrict__ knope,
    const f16* __restrict__ kper, const f16* __restrict__ vf,
    f16* __restrict__ aout)
{
  int qt = blockIdx.x, h = blockIdx.y, b = blockIdx.z;
  int q0 = qt * 128;
  int tid = threadIdx.x, lane = tid & 63, wv = tid >> 6;
  int lrow = lane & 15, lk = lane >> 4;

  __shared__ __align__(16) f16 Ks[64 * 192];
  __shared__ __align__(16) f16 Vs[128 * 64];
  __shared__ __align__(16) f16 Ps[4][32 * 72];

  // Q fragments: rows q0 + wv*32 + m*16 + lrow, direct from qraw
  f16x8 qfr[2][6];
#pragma unroll
  for (int m = 0; m < 2; ++m) {
    const f16* qb = qraw + ((size_t)(b * 2048 + q0 + wv * 32 + m * 16 + lrow)) * 3072
                    + h * 192 + lk * 8;
#pragma unroll
    for (int ks = 0; ks < 6; ++ks) qfr[m][ks] = *(const f16x8*)(qb + ks * 32);
  }

  f32x4 oacc[2][8];
#pragma unroll
  for (int m = 0; m < 2; ++m)
#pragma unroll
    for (int i = 0; i < 8; ++i) oacc[m][i] = f32x4{0.f, 0.f, 0.f, 0.f};
  float m_st[2][4], l_st[2][4];
#pragma unroll
  for (int m = 0; m < 2; ++m)
#pragma unroll
    for (int r = 0; r < 4; ++r) { m_st[m][r] = -1e30f; l_st[m][r] = 0.f; }

  const f16* knb = knope + ((size_t)b * 2048) * 2048 + h * 128;
  const f16* kpb = kper + (size_t)b * 2048 * 64;
  const f16* vb_ = vf + ((size_t)(b * 16 + h)) * 128 * 2048;

  // precomputed staging descriptors (ptr at t0=0 + per-iter byte step)
  const char* kp_ptr[6]; int kp_step[6];
#pragma unroll
  for (int it = 0; it < 6; ++it) {
    int s = it * 256 + tid;
    int r = s / 24, c = s - r * 24;
    int gc = c ^ (r & 7);
    if (gc < 16) { kp_ptr[it] = (const char*)(knb + (size_t)r * 2048 + gc * 8); kp_step[it] = 64 * 2048 * 2; }
    else         { kp_ptr[it] = (const char*)(kpb + (size_t)r * 64 + (gc - 16) * 8); kp_step[it] = 64 * 64 * 2; }
  }
  const char* vp_ptr[4];
#pragma unroll
  for (int it = 0; it < 4; ++it) {
    int s = it * 256 + tid;
    int r = s >> 3, c = s & 7, gc = c ^ (r & 7);
    vp_ptr[it] = (const char*)(vb_ + (size_t)r * 2048 + gc * 8);
  }

  for (int t0 = 0; t0 < 2048; t0 += 64) {
    __syncthreads();
#pragma unroll
    for (int it = 0; it < 6; ++it) {
      gl2lds16(kp_ptr[it], (f16*)Ks + (size_t)(it * 256 + wv * 64) * 8);
      kp_ptr[it] += kp_step[it];
    }
#pragma unroll
    for (int it = 0; it < 4; ++it) {
      gl2lds16(vp_ptr[it], (f16*)Vs + (size_t)(it * 256 + wv * 64) * 8);
      vp_ptr[it] += 64 * 2;
    }
    __syncthreads();

    // S = Q K^T : 32 q-rows x 64 keys per wave (B-frags shared across m)
    f32x4 sacc[2][4];
#pragma unroll
    for (int m = 0; m < 2; ++m)
#pragma unroll
      for (int nt = 0; nt < 4; ++nt) sacc[m][nt] = f32x4{0.f, 0.f, 0.f, 0.f};
#pragma unroll
    for (int nt = 0; nt < 4; ++nt) {
      int rb = nt * 16 + lrow;
#pragma unroll
      for (int ks = 0; ks < 6; ++ks) {
        int cc = (ks * 4 + lk) ^ (rb & 7);
        f16x8 bfr = *(const f16x8*)(Ks + rb * 192 + cc * 8);
        sacc[0][nt] = __builtin_amdgcn_mfma_f32_16x16x32_f16(qfr[0][ks], bfr, sacc[0][nt], 0, 0, 0);
        sacc[1][nt] = __builtin_amdgcn_mfma_f32_16x16x32_f16(qfr[1][ks], bfr, sacc[1][nt], 0, 0, 0);
      }
    }

    // online softmax (fp32 SCALE, __expf, per-iter l all-reduce)
    float alpha[2][4];
#pragma unroll
    for (int m = 0; m < 2; ++m) {
#pragma unroll
      for (int r = 0; r < 4; ++r) {
        float z0 = sacc[m][0][r] * SCALE, z1 = sacc[m][1][r] * SCALE;
        float z2 = sacc[m][2][r] * SCALE, z3 = sacc[m][3][r] * SCALE;
        float mx = fmaxf(fmaxf(z0, z1), fmaxf(z2, z3));
#pragma unroll
        for (int msk = 1; msk < 16; msk <<= 1) mx = fmaxf(mx, __shfl_xor(mx, msk));
        float mnew = fmaxf(m_st[m][r], mx);
        float al = __expf(m_st[m][r] - mnew);
        float p0 = __expf(z0 - mnew), p1 = __expf(z1 - mnew);
        float p2 = __expf(z2 - mnew), p3 = __expf(z3 - mnew);
        float ls = p0 + p1 + p2 + p3;
#pragma unroll
        for (int msk = 1; msk < 16; msk <<= 1) ls += __shfl_xor(ls, msk);
        l_st[m][r] = l_st[m][r] * al + ls;
        m_st[m][r] = mnew;
        alpha[m][r] = al;
        int prow = (m * 16 + lk * 4 + r) * 72;
        Ps[wv][prow + 0 * 16 + lrow] = (f16)p0;
        Ps[wv][prow + 1 * 16 + lrow] = (f16)p1;
        Ps[wv][prow + 2 * 16 + lrow] = (f16)p2;
        Ps[wv][prow + 3 * 16 + lrow] = (f16)p3;
      }
    }
#pragma unroll
    for (int m = 0; m < 2; ++m)
#pragma unroll
      for (int nv = 0; nv < 8; ++nv) {
        oacc[m][nv][0] *= alpha[m][0]; oacc[m][nv][1] *= alpha[m][1];
        oacc[m][nv][2] *= alpha[m][2]; oacc[m][nv][3] *= alpha[m][3];
      }
    __builtin_amdgcn_s_waitcnt(0xC07F);   // lgkmcnt(0): own P writes visible

    // O += P V  (V^T B-frags shared across m)
#pragma unroll
    for (int ks2 = 0; ks2 < 2; ++ks2) {
      f16x8 pa0 = *(const f16x8*)(&Ps[wv][(0 * 16 + lrow) * 72 + ks2 * 32 + lk * 8]);
      f16x8 pa1 = *(const f16x8*)(&Ps[wv][(1 * 16 + lrow) * 72 + ks2 * 32 + lk * 8]);
#pragma unroll
      for (int nv = 0; nv < 8; ++nv) {
        int rv = nv * 16 + lrow;
        int cc = (ks2 * 4 + lk) ^ (rv & 7);
        f16x8 vbf = *(const f16x8*)(Vs + rv * 64 + cc * 8);
        oacc[0][nv] = __builtin_amdgcn_mfma_f32_16x16x32_f16(pa0, vbf, oacc[0][nv], 0, 0, 0);
        oacc[1][nv] = __builtin_amdgcn_mfma_f32_16x16x32_f16(pa1, vbf, oacc[1][nv], 0, 0, 0);
      }
    }
  }

  float rinv[2][4];
#pragma unroll
  for (int m = 0; m < 2; ++m)
#pragma unroll
    for (int r = 0; r < 4; ++r) rinv[m][r] = 1.0f / l_st[m][r];
#pragma unroll
  for (int m = 0; m < 2; ++m) {
    f16* ob = aout + ((size_t)(b * 2048 + q0 + wv * 32 + m * 16 + lk * 4)) * 2048
              + h * 128 + lrow;
#pragma unroll
    for (int nv = 0; nv < 8; ++nv)
#pragma unroll
      for (int rr = 0; rr < 4; ++rr)
        ob[(size_t)rr * 2048 + nv * 16] = (f16)(oacc[m][nv][rr] * rinv[m][rr]);
  }
}

// ---------------------------------------------------------------------------
extern "C" void kernel_launch(void* const* d_in, const int* in_sizes, int n_in,
                              void* d_out, int out_size, void* d_ws, size_t ws_size,
                              hipStream_t stream)
{
  const float* x    = (const float*)d_in[0];
  const float* cosb = (const float*)d_in[1];
  const float* sinb = (const float*)d_in[2];
  const float* wq   = (const float*)d_in[3];
  const float* wkva = (const float*)d_in[4];
  const float* knw  = (const float*)d_in[5];
  const float* wkvb = (const float*)d_in[6];
  const float* wo   = (const float*)d_in[7];
  float* out = (float*)d_out;

  char* p = (char*)d_ws;
  auto take = [&](size_t elems) { char* r = p; p += (elems * 2 + 255) & ~(size_t)255; return r; };
  f16* xb    = (f16*)take(8388608ull);    // x f16          (4096x2048)
  f16* wqb   = (f16*)take(6291456ull);    // wq f16         (3072x2048)
  f16* wkvab = (f16*)take(1310720ull);    // wkv_a padded   (640x2048)
  f16* wkvbb = (f16*)take(2097152ull);    // wkv_b f16      (4096x512)
  f16* wob   = (f16*)take(4194304ull);    // wo f16         (2048x2048)
  f16* qraw  = (f16*)take(12582912ull);   // q proj, roped in place (4096x3072)
  f16* kva   = (f16*)take(2621440ull);    // kv_a out       (4096x640)
  f16* kvn   = (f16*)take(2097152ull);    // rmsnormed kv   (4096x512)
  f16* kper  = (f16*)take(262144ull);     // roped k_pe     (4096x64)
  f16* knope = (f16*)take(8388608ull);    // k_nope         (4096x2048)
  f16* vf    = (f16*)take(8388608ull);    // V^T (b,h,128,2048) = 8M elems (FIXED)
  f16* aout  = (f16*)take(8388608ull);    // attn out       (4096x2048)

  k_cvt<<<20480, 256, 0, stream>>>(x, wq, wkvb, wo, xb, wqb, wkvbb, wob);
  k_cvt_pad<<<1280, 256, 0, stream>>>(wkva, wkvab);
  k_gemm_qkva<<<dim3(29, 32), 256, 0, stream>>>(xb, wqb, wkvab, qraw, kva);
  k_rmsnorm_rope<<<4096, 256, 0, stream>>>(kva, knw, cosb, sinb, kvn, kper);
  k_rope_q<<<8192, 256, 0, stream>>>(qraw, cosb, sinb);
  k_gemm_kvb<<<dim3(32, 32), 256, 0, stream>>>(kvn, wkvbb, knope, vf);
  k_attn<<<dim3(16, 16, 2), 256, 0, stream>>>(qraw, knope, kper, vf, aout);
  k_gemm_out<<<dim3(16, 32), 256, 0, stream>>>(aout, wob, out);
}